// Round 6
// baseline (356.833 us; speedup 1.0000x reference)
//
#include <hip/hip_runtime.h>

typedef __attribute__((ext_vector_type(8))) short short8;
typedef __attribute__((ext_vector_type(4))) float f32x4;

__device__ __forceinline__ unsigned short f2bf(float f) {
  union { float f; unsigned u; } v; v.f = f;
  unsigned u = v.u + 0x7fffu + ((v.u >> 16) & 1u);
  return (unsigned short)(u >> 16);
}
__device__ __forceinline__ float bflo(unsigned u) {
  union { unsigned u; float f; } v; v.u = u << 16; return v.f;
}
__device__ __forceinline__ float bfhi(unsigned u) {
  union { unsigned u; float f; } v; v.u = u & 0xffff0000u; return v.f;
}
// v_cvt_pk_bf16_f32: 2 fp32 -> packed 2 bf16 (RNE), 1 inst
__device__ __forceinline__ unsigned cvtpk(float lo, float hi) {
  unsigned r;
  asm("v_cvt_pk_bf16_f32 %0, %1, %2" : "=v"(r) : "v"(lo), "v"(hi));
  return r;
}
typedef unsigned int u32;
typedef u32 __attribute__((address_space(3)))* lds_u32p;
typedef const u32 __attribute__((address_space(1)))* glob_u32p;
__device__ __forceinline__ void glds16(const unsigned short* g, unsigned short* l) {
  __builtin_amdgcn_global_load_lds((glob_u32p)(const void*)g, (lds_u32p)(void*)l,
                                   16, 0, 0);
}

// ---------------- fp32 -> bf16 cast (x, adj-slice, weights) ---------------
__global__ __launch_bounds__(256) void cast_kernel(
    const float* __restrict__ in, unsigned short* __restrict__ out, int n8) {
  int i = blockIdx.x * 256 + threadIdx.x;
  if (i >= n8) return;
  const float* p = in + (size_t)i * 8;
  float4 f0 = *(const float4*)p;
  float4 f1 = *(const float4*)(p + 4);
  uint4 w;
  w.x = cvtpk(f0.x, f0.y); w.y = cvtpk(f0.z, f0.w);
  w.z = cvtpk(f1.x, f1.y); w.w = cvtpk(f1.z, f1.w);
  *(uint4*)(out + (size_t)i * 8) = w;
}

// ====== gemm_bt 128x128xBK64 — R2/R5 single-buffer m97 structure ==========
// REP: diagnostic knob — repeats the whole K-loop REP times inside one
// dispatch (acc kept live via asm, zeroed between reps; only last written).
// Output is bit-identical to REP=1; duration ~REP x.  Used to lift the spmm
// above the harness fill dispatches so rocprof top-5 shows its counters.
template<int BIAS_MODE, int RELU, int REP>
__global__ __launch_bounds__(256)
void gemm128(const unsigned short* __restrict__ Ab,
             const unsigned short* __restrict__ Bb,
             unsigned short* __restrict__ Cv, const float* __restrict__ biasv,
             int K, int lda, int ldb, int ldc,
             long long sA, long long sB, long long sC, int sBias)
{
  __shared__ __align__(16) unsigned short lA[128 * 64];
  __shared__ __align__(16) unsigned short lB[128 * 64];

  // bijective XCD swizzle (grid 384 = 48/XCD)
  const int gx = gridDim.x, gy = gridDim.y;
  const int bid = blockIdx.x + gx * (blockIdx.y + gy * blockIdx.z);
  const int nwg = gx * gy * gridDim.z;
  const int s   = (bid & 7) * (nwg >> 3) + (bid >> 3);
  const int bx  = s % gx;
  const int by  = (s / gx) % gy;
  const int t   = s / (gx * gy);

  const int row0 = by * 128;
  const int col0 = bx * 128;

  const unsigned short* A = Ab + (size_t)t * sA;
  const unsigned short* B = Bb + (size_t)t * sB;
  unsigned short*       C = Cv + (size_t)t * sC;

  const int tid  = threadIdx.x;
  const int lane = tid & 63;
  const int wave = tid >> 6;
  const int wr   = wave >> 1;          // 0..1 (M half)
  const int wc   = wave & 1;           // 0..1 (N half)
  const int fr   = lane & 15;
  const int fk   = (lane >> 4) << 3;

  const int grow = lane >> 3;          // glds: +row within 8-row segment
  const int gcol = (lane & 7) << 3;    // glds: stored col (pre-swizzle)

  f32x4 acc[4][4] = {};

  for (int rep = 0; rep < REP; ++rep) {
    for (int k0 = 0; k0 < K; k0 += 64) {
      __syncthreads();
      #pragma unroll
      for (int i = 0; i < 4; ++i) {
        int seg = i * 4 + wave;
        int r   = seg * 8 + grow;
        int c   = gcol ^ ((r & 7) << 3);
        glds16(A + (size_t)(row0 + r) * lda + k0 + c, &lA[seg * 512]);
        glds16(B + (size_t)(col0 + r) * ldb + k0 + c, &lB[seg * 512]);
      }
      __syncthreads();   // compiler drains vmcnt here

      #pragma unroll
      for (int kk = 0; kk < 2; ++kk) {
        short8 af[4], bv[4];
        #pragma unroll
        for (int mi = 0; mi < 4; ++mi) {
          int r = wr * 64 + mi * 16 + fr;
          af[mi] = *(const short8*)&lA[r * 64 + ((kk * 32 + fk) ^ ((r & 7) << 3))];
        }
        #pragma unroll
        for (int ni = 0; ni < 4; ++ni) {
          int r = wc * 64 + ni * 16 + fr;
          bv[ni] = *(const short8*)&lB[r * 64 + ((kk * 32 + fk) ^ ((r & 7) << 3))];
        }
        #pragma unroll
        for (int mi = 0; mi < 4; ++mi)
          #pragma unroll
          for (int ni = 0; ni < 4; ++ni)
            acc[mi][ni] = __builtin_amdgcn_mfma_f32_16x16x32_bf16(
                af[mi], bv[ni], acc[mi][ni], 0, 0, 0);
      }
    }
    if (rep != REP - 1) {
      // keep rep's results live (anti-DCE, rule #17), then reset acc
      #pragma unroll
      for (int mi = 0; mi < 4; ++mi)
        #pragma unroll
        for (int ni = 0; ni < 4; ++ni) {
          asm volatile("" :: "v"(acc[mi][ni][0]), "v"(acc[mi][ni][1]),
                             "v"(acc[mi][ni][2]), "v"(acc[mi][ni][3]));
          acc[mi][ni] = f32x4{0.f, 0.f, 0.f, 0.f};
        }
    }
  }

  const float* bias = nullptr;
  if constexpr (BIAS_MODE != 0) bias = biasv + (size_t)t * sBias;
  const int erow = (lane >> 4) << 2;
  #pragma unroll
  for (int mi = 0; mi < 4; ++mi) {
    #pragma unroll
    for (int ni = 0; ni < 4; ++ni) {
      #pragma unroll
      for (int j = 0; j < 4; ++j) {
        int row = row0 + wr * 64 + mi * 16 + erow + j;
        int col = col0 + wc * 64 + ni * 16 + fr;
        float v = acc[mi][ni][j];
        if constexpr (BIAS_MODE == 1) v += bias[row];
        if constexpr (BIAS_MODE == 2) v += bias[col];
        if constexpr (RELU) v = fmaxf(v, 0.0f);
        C[(size_t)row * ldc + col] = f2bf(v);
      }
    }
  }
}

// ---------------- head: logits = feat @ W_lin^T + b, then log_softmax -----
__global__ __launch_bounds__(256)
void head_kernel(const unsigned short* __restrict__ h2,
                 const float* __restrict__ Wl,
                 const float* __restrict__ blin,
                 float* __restrict__ out)
{
  const int tid = threadIdx.x;
  const int c   = tid & 31;
  const int rg  = tid >> 5;
  const int i0  = blockIdx.x * 16;
  const int r0  = i0 + rg;
  const int r1  = i0 + rg + 8;
  float acc0 = 0.f, acc1 = 0.f;
  #pragma unroll
  for (int t = 0; t < 3; ++t) {
    const unsigned short* x0 = h2 + (size_t)t * 2097152 + (size_t)r0 * 512;
    const unsigned short* x1 = h2 + (size_t)t * 2097152 + (size_t)r1 * 512;
    const float* wt = Wl + (size_t)c * 1536 + t * 512;
    #pragma unroll 4
    for (int k = 0; k < 512; k += 8) {
      float4 w0 = *(const float4*)(wt + k);
      float4 w1 = *(const float4*)(wt + k + 4);
      uint4 a0 = *(const uint4*)(x0 + k);
      uint4 a1 = *(const uint4*)(x1 + k);
      const unsigned* u0 = (const unsigned*)&a0;
      const unsigned* u1 = (const unsigned*)&a1;
      const float* wf = (const float*)&w0;
      #pragma unroll
      for (int q = 0; q < 2; ++q) {
        acc0 += bflo(u0[q]) * wf[2*q] + bfhi(u0[q]) * wf[2*q+1];
        acc1 += bflo(u1[q]) * wf[2*q] + bfhi(u1[q]) * wf[2*q+1];
      }
      const float* wg = (const float*)&w1;
      #pragma unroll
      for (int q = 0; q < 2; ++q) {
        acc0 += bflo(u0[q+2]) * wg[2*q] + bfhi(u0[q+2]) * wg[2*q+1];
        acc1 += bflo(u1[q+2]) * wg[2*q] + bfhi(u1[q+2]) * wg[2*q+1];
      }
    }
  }
  acc0 += blin[c]; acc1 += blin[c];
  float m0 = acc0, m1 = acc1;
  #pragma unroll
  for (int s = 16; s; s >>= 1) {
    m0 = fmaxf(m0, __shfl_xor(m0, s, 32));
    m1 = fmaxf(m1, __shfl_xor(m1, s, 32));
  }
  float e0 = expf(acc0 - m0), e1 = expf(acc1 - m1);
  #pragma unroll
  for (int s = 16; s; s >>= 1) {
    e0 += __shfl_xor(e0, s, 32);
    e1 += __shfl_xor(e1, s, 32);
  }
  out[(size_t)r0 * 32 + c] = acc0 - m0 - logf(e0);
  out[(size_t)r1 * 32 + c] = acc1 - m1 - logf(e1);
}

extern "C" void kernel_launch(void* const* d_in, const int* in_sizes, int n_in,
                              void* d_out, int out_size, void* d_ws, size_t ws_size,
                              hipStream_t stream)
{
  const float* x      = (const float*)d_in[0];
  const float* adj    = (const float*)d_in[1];
  // d_in[2] = node_type_mask (unused: contiguous equal blocks by construction)
  const float* W_conv = (const float*)d_in[3];
  const float* b_conv = (const float*)d_in[4];
  const float* W_sage = (const float*)d_in[5];
  const float* b_sage = (const float*)d_in[6];
  const float* W_lin  = (const float*)d_in[7];
  const float* b_lin  = (const float*)d_in[8];
  float* out = (float*)d_out;

  // workspace (bf16 elems)
  unsigned short* ws   = (unsigned short*)d_ws;
  unsigned short* xbf  = ws;                    //  6,291,456  (x bf16)
  unsigned short* adjb = xbf  + 6291456;        // 50,331,648  (adj[0:4096,:] bf16)
  unsigned short* Wc   = adjb + 50331648;       //    786,432
  unsigned short* Wsg  = Wc   + 786432;         //    786,432
  unsigned short* ht   = Wsg  + 786432;         //  6,291,456  (h^T; later h2)
  unsigned short* m_   = ht   + 6291456;        //  6,291,456
  unsigned short* h2   = ht;

  cast_kernel<<<3072,  256, 0, stream>>>(x, xbf, 786432);
  cast_kernel<<<24576, 256, 0, stream>>>(adj, adjb, 6291456);
  cast_kernel<<<384,   256, 0, stream>>>(W_conv, Wc, 98304);
  cast_kernel<<<384,   256, 0, stream>>>(W_sage, Wsg, 98304);

  // GEMM1: ht[t] = relu(W_conv[t] @ xs[t]^T + b_conv[t])  [512 x 4096]
  gemm128<1, 1, 1><<<dim3(32, 4, 3), 256, 0, stream>>>(
      Wc, xbf, ht, b_conv, 512, 512, 512, 4096,
      262144LL, 2097152LL, 2097152LL, 512);

  // GEMM2 (spmm): m[t] = adj_b[t] @ h[t]  [4096 x 512]  --- REP=3 DIAGNOSTIC
  gemm128<0, 0, 3><<<dim3(4, 32, 3), 256, 0, stream>>>(
      adjb, ht, m_, nullptr, 4096, 12288, 4096, 512,
      4096LL, 2097152LL, 2097152LL, 0);

  // GEMM3: h2[t] = relu(m[t] @ W_sage[t]^T + b_sage[t])  [4096 x 512]
  gemm128<2, 1, 1><<<dim3(4, 32, 3), 256, 0, stream>>>(
      m_, Wsg, h2, b_sage, 512, 512, 512, 512,
      2097152LL, 262144LL, 2097152LL, 512);

  head_kernel<<<256, 256, 0, stream>>>(h2, W_lin, b_lin, out);
}

// Round 8
// 267.192 us; speedup vs baseline: 1.3355x; 1.3355x over previous
//
#include <hip/hip_runtime.h>

typedef __attribute__((ext_vector_type(8))) short short8;
typedef __attribute__((ext_vector_type(4))) float f32x4;

__device__ __forceinline__ unsigned short f2bf(float f) {
  union { float f; unsigned u; } v; v.f = f;
  unsigned u = v.u + 0x7fffu + ((v.u >> 16) & 1u);
  return (unsigned short)(u >> 16);
}
__device__ __forceinline__ float bflo(unsigned u) {
  union { unsigned u; float f; } v; v.u = u << 16; return v.f;
}
__device__ __forceinline__ float bfhi(unsigned u) {
  union { unsigned u; float f; } v; v.u = u & 0xffff0000u; return v.f;
}
// v_cvt_pk_bf16_f32: 2 fp32 -> packed 2 bf16 (RNE), 1 inst
__device__ __forceinline__ unsigned cvtpk(float lo, float hi) {
  unsigned r;
  asm("v_cvt_pk_bf16_f32 %0, %1, %2" : "=v"(r) : "v"(lo), "v"(hi));
  return r;
}
typedef unsigned int u32;
typedef u32 __attribute__((address_space(3)))* lds_u32p;
typedef const u32 __attribute__((address_space(1)))* glob_u32p;
__device__ __forceinline__ void glds16(const unsigned short* g, unsigned short* l) {
  __builtin_amdgcn_global_load_lds((glob_u32p)(const void*)g, (lds_u32p)(void*)l,
                                   16, 0, 0);
}
__device__ __forceinline__ void cast8(const float* p, unsigned short* o) {
  float4 f0 = *(const float4*)p;
  float4 f1 = *(const float4*)(p + 4);
  uint4 w;
  w.x = cvtpk(f0.x, f0.y); w.y = cvtpk(f0.z, f0.w);
  w.z = cvtpk(f1.x, f1.y); w.w = cvtpk(f1.z, f1.w);
  *(uint4*)o = w;
}

// ====== gemm body 128x128xBK64 — R5-proven single-buffer m97 structure ====
// C[MxN](bf16) = op(A[MxK] @ Bt[NxK]^T).  s in [0, GX*GY*3) decodes
// (bx,by,t).  Operands: bf16 -> global_load_lds_dwordx4 with pre-swizzled
// source col (rule #21); fp32 -> reg-load + v_cvt_pk_bf16_f32 + swizzled
// ds_write (R4-proven).  LDS elem(row,col) at [row*64 + (col^((row&7)<<3))].
// BIAS_MODE: 0 none, 1 per-row, 2 per-col.
template<int GX, int GY, int A_F32, int B_F32, int BIAS_MODE, int RELU>
__device__ __forceinline__ void gemm_body(int s,
    const void* __restrict__ Av, const void* __restrict__ Bv,
    unsigned short* __restrict__ Cv, const float* __restrict__ biasv,
    int K, int lda, int ldb, int ldc,
    long long sA, long long sB, long long sC, int sBias,
    unsigned short* lA, unsigned short* lB)
{
  const int bx = s % GX;
  const int by = (s / GX) % GY;
  const int t  = s / (GX * GY);
  const int row0 = by * 128, col0 = bx * 128;

  const unsigned short* Ab = (const unsigned short*)Av + (size_t)t * sA;
  const float*          Af = (const float*)Av + (size_t)t * sA;
  const unsigned short* Bb = (const unsigned short*)Bv + (size_t)t * sB;
  const float*          Bf = (const float*)Bv + (size_t)t * sB;
  unsigned short*       C  = Cv + (size_t)t * sC;

  const int tid  = threadIdx.x;
  const int lane = tid & 63;
  const int wave = tid >> 6;
  const int wr   = wave >> 1;          // 0..1 (M half)
  const int wc   = wave & 1;           // 0..1 (N half)
  const int fr   = lane & 15;
  const int fk   = (lane >> 4) << 3;
  const int grow = lane >> 3;          // glds: +row within 8-row segment
  const int gcol = (lane & 7) << 3;    // glds: stored col (pre-swizzle)
  const int srow = tid >> 1;           // fp32 stage: 0..127
  const int scol = (tid & 1) << 5;     // 0 / 32

  f32x4 acc[4][4] = {};

  for (int k0 = 0; k0 < K; k0 += 64) {
    __syncthreads();
    // ---- stage A ----
    if constexpr (A_F32) {
      const float* p = Af + (size_t)(row0 + srow) * lda + k0 + scol;
      float4 f[8];
      #pragma unroll
      for (int j = 0; j < 8; ++j) f[j] = *(const float4*)(p + j * 4);
      #pragma unroll
      for (int j = 0; j < 4; ++j) {
        uint4 w;
        w.x = cvtpk(f[2*j].x,   f[2*j].y);
        w.y = cvtpk(f[2*j].z,   f[2*j].w);
        w.z = cvtpk(f[2*j+1].x, f[2*j+1].y);
        w.w = cvtpk(f[2*j+1].z, f[2*j+1].w);
        *(uint4*)&lA[srow * 64 + ((scol + j * 8) ^ ((srow & 7) << 3))] = w;
      }
    } else {
      #pragma unroll
      for (int i = 0; i < 4; ++i) {
        int seg = i * 4 + wave;
        int r   = seg * 8 + grow;
        glds16(Ab + (size_t)(row0 + r) * lda + k0 + (gcol ^ ((r & 7) << 3)),
               &lA[seg * 512]);
      }
    }
    // ---- stage B ----
    if constexpr (B_F32) {
      const float* p = Bf + (size_t)(col0 + srow) * ldb + k0 + scol;
      float4 f[8];
      #pragma unroll
      for (int j = 0; j < 8; ++j) f[j] = *(const float4*)(p + j * 4);
      #pragma unroll
      for (int j = 0; j < 4; ++j) {
        uint4 w;
        w.x = cvtpk(f[2*j].x,   f[2*j].y);
        w.y = cvtpk(f[2*j].z,   f[2*j].w);
        w.z = cvtpk(f[2*j+1].x, f[2*j+1].y);
        w.w = cvtpk(f[2*j+1].z, f[2*j+1].w);
        *(uint4*)&lB[srow * 64 + ((scol + j * 8) ^ ((srow & 7) << 3))] = w;
      }
    } else {
      #pragma unroll
      for (int i = 0; i < 4; ++i) {
        int seg = i * 4 + wave;
        int r   = seg * 8 + grow;
        glds16(Bb + (size_t)(col0 + r) * ldb + k0 + (gcol ^ ((r & 7) << 3)),
               &lB[seg * 512]);
      }
    }
    __syncthreads();   // drains vmcnt (glds) + lgkm (ds_write)

    #pragma unroll
    for (int kk = 0; kk < 2; ++kk) {
      short8 af[4], bv[4];
      #pragma unroll
      for (int mi = 0; mi < 4; ++mi) {
        int r = wr * 64 + mi * 16 + fr;
        af[mi] = *(const short8*)&lA[r * 64 + ((kk * 32 + fk) ^ ((r & 7) << 3))];
      }
      #pragma unroll
      for (int ni = 0; ni < 4; ++ni) {
        int r = wc * 64 + ni * 16 + fr;
        bv[ni] = *(const short8*)&lB[r * 64 + ((kk * 32 + fk) ^ ((r & 7) << 3))];
      }
      #pragma unroll
      for (int mi = 0; mi < 4; ++mi)
        #pragma unroll
        for (int ni = 0; ni < 4; ++ni)
          acc[mi][ni] = __builtin_amdgcn_mfma_f32_16x16x32_bf16(
              af[mi], bv[ni], acc[mi][ni], 0, 0, 0);
    }
  }

  const float* bias = nullptr;
  if constexpr (BIAS_MODE != 0) bias = biasv + (size_t)t * sBias;
  const int erow = (lane >> 4) << 2;
  #pragma unroll
  for (int mi = 0; mi < 4; ++mi) {
    #pragma unroll
    for (int ni = 0; ni < 4; ++ni) {
      #pragma unroll
      for (int j = 0; j < 4; ++j) {
        int row = row0 + wr * 64 + mi * 16 + erow + j;
        int col = col0 + wc * 64 + ni * 16 + fr;
        float v = acc[mi][ni][j];
        if constexpr (BIAS_MODE == 1) v += bias[row];
        if constexpr (BIAS_MODE == 2) v += bias[col];
        if constexpr (RELU) v = fmaxf(v, 0.0f);
        C[(size_t)row * ldc + col] = f2bf(v);
      }
    }
  }
}

// bijective XCD swizzle over nwg blocks (nwg % 8 == 0)
__device__ __forceinline__ int xcd_swz(int bid, int nwg) {
  return (bid & 7) * (nwg >> 3) + (bid >> 3);
}

// ---- d1: blocks [0,384) gemm1 (A=W_conv fp32, B=x fp32, bias row, relu);
//          blocks [384, 2304) grid-stride adj fp32 -> bf16 cast.
__global__ __launch_bounds__(256)
void k_gemm1_adjcast(const float* __restrict__ W_conv, const float* __restrict__ x,
                     unsigned short* __restrict__ ht, const float* __restrict__ b_conv,
                     const float* __restrict__ adj, unsigned short* __restrict__ adjb)
{
  __shared__ __align__(16) unsigned short lA[128 * 64];
  __shared__ __align__(16) unsigned short lB[128 * 64];
  const int bid = blockIdx.x;
  if (bid < 384) {
    gemm_body<32, 4, 1, 1, 1, 1>(xcd_swz(bid, 384), W_conv, x, ht, b_conv,
                                 512, 512, 512, 4096,
                                 262144LL, 2097152LL, 2097152LL, 512, lA, lB);
  } else {
    const size_t stride = (size_t)(2304 - 384) * 256;
    for (size_t i = (size_t)(bid - 384) * 256 + threadIdx.x; i < 6291456u;
         i += stride)
      cast8(adj + i * 8, adjb + i * 8);
  }
}

// ---- generic gemm dispatch (spmm, gemm3) ----
template<int GX, int GY, int A_F32, int B_F32, int BIAS_MODE, int RELU>
__global__ __launch_bounds__(256)
void k_gemm(const void* __restrict__ Av, const void* __restrict__ Bv,
            unsigned short* __restrict__ Cv, const float* __restrict__ biasv,
            int K, int lda, int ldb, int ldc,
            long long sA, long long sB, long long sC, int sBias)
{
  __shared__ __align__(16) unsigned short lA[128 * 64];
  __shared__ __align__(16) unsigned short lB[128 * 64];
  gemm_body<GX, GY, A_F32, B_F32, BIAS_MODE, RELU>(
      xcd_swz(blockIdx.x, GX * GY * 3), Av, Bv, Cv, biasv,
      K, lda, ldb, ldc, sA, sB, sC, sBias, lA, lB);
}

// ---------------- head: logits = feat @ W_lin^T + b, then log_softmax -----
__global__ __launch_bounds__(256)
void head_kernel(const unsigned short* __restrict__ h2,
                 const float* __restrict__ Wl,
                 const float* __restrict__ blin,
                 float* __restrict__ out)
{
  const int tid = threadIdx.x;
  const int c   = tid & 31;
  const int rg  = tid >> 5;
  const int i0  = blockIdx.x * 16;
  const int r0  = i0 + rg;
  const int r1  = i0 + rg + 8;
  float acc0 = 0.f, acc1 = 0.f;
  #pragma unroll
  for (int t = 0; t < 3; ++t) {
    const unsigned short* x0 = h2 + (size_t)t * 2097152 + (size_t)r0 * 512;
    const unsigned short* x1 = h2 + (size_t)t * 2097152 + (size_t)r1 * 512;
    const float* wt = Wl + (size_t)c * 1536 + t * 512;
    #pragma unroll 4
    for (int k = 0; k < 512; k += 8) {
      float4 w0 = *(const float4*)(wt + k);
      float4 w1 = *(const float4*)(wt + k + 4);
      uint4 a0 = *(const uint4*)(x0 + k);
      uint4 a1 = *(const uint4*)(x1 + k);
      const unsigned* u0 = (const unsigned*)&a0;
      const unsigned* u1 = (const unsigned*)&a1;
      const float* wf = (const float*)&w0;
      #pragma unroll
      for (int q = 0; q < 2; ++q) {
        acc0 += bflo(u0[q]) * wf[2*q] + bfhi(u0[q]) * wf[2*q+1];
        acc1 += bflo(u1[q]) * wf[2*q] + bfhi(u1[q]) * wf[2*q+1];
      }
      const float* wg = (const float*)&w1;
      #pragma unroll
      for (int q = 0; q < 2; ++q) {
        acc0 += bflo(u0[q+2]) * wg[2*q] + bfhi(u0[q+2]) * wg[2*q+1];
        acc1 += bflo(u1[q+2]) * wg[2*q] + bfhi(u1[q+2]) * wg[2*q+1];
      }
    }
  }
  acc0 += blin[c]; acc1 += blin[c];
  float m0 = acc0, m1 = acc1;
  #pragma unroll
  for (int s2 = 16; s2; s2 >>= 1) {
    m0 = fmaxf(m0, __shfl_xor(m0, s2, 32));
    m1 = fmaxf(m1, __shfl_xor(m1, s2, 32));
  }
  float e0 = expf(acc0 - m0), e1 = expf(acc1 - m1);
  #pragma unroll
  for (int s2 = 16; s2; s2 >>= 1) {
    e0 += __shfl_xor(e0, s2, 32);
    e1 += __shfl_xor(e1, s2, 32);
  }
  out[(size_t)r0 * 32 + c] = acc0 - m0 - logf(e0);
  out[(size_t)r1 * 32 + c] = acc1 - m1 - logf(e1);
}

extern "C" void kernel_launch(void* const* d_in, const int* in_sizes, int n_in,
                              void* d_out, int out_size, void* d_ws, size_t ws_size,
                              hipStream_t stream)
{
  const float* x      = (const float*)d_in[0];
  const float* adj    = (const float*)d_in[1];
  // d_in[2] = node_type_mask (unused: contiguous equal blocks by construction)
  const float* W_conv = (const float*)d_in[3];
  const float* b_conv = (const float*)d_in[4];
  const float* W_sage = (const float*)d_in[5];
  const float* b_sage = (const float*)d_in[6];
  const float* W_lin  = (const float*)d_in[7];
  const float* b_lin  = (const float*)d_in[8];
  float* out = (float*)d_out;

  // workspace (bf16 elems); h2 reuses ht (ht dead after spmm)
  unsigned short* ws   = (unsigned short*)d_ws;
  unsigned short* adjb = ws;                    // 50,331,648 (adj[0:4096,:] bf16)
  unsigned short* ht   = adjb + 50331648;       //  6,291,456 (h^T [3][512][4096])
  unsigned short* m_   = ht   + 6291456;        //  6,291,456 ([3][4096][512])
  unsigned short* h2   = ht;

  // d1: gemm1 (self-contained fp32 operands) || adj cast
  k_gemm1_adjcast<<<2304, 256, 0, stream>>>(W_conv, x, ht, b_conv, adj, adjb);

  // d2 (spmm): m[t] = adj_b[t] @ h[t]   A=adjb bf16 (lda=12288, +t*4096 cols)
  k_gemm<4, 32, 0, 0, 0, 0><<<384, 256, 0, stream>>>(
      adjb, ht, m_, nullptr, 4096, 12288, 4096, 512,
      4096LL, 2097152LL, 2097152LL, 0);

  // d3: h2[t] = relu(m[t] @ W_sage[t]^T + b_sage[t])   B=W_sage fp32 cvt
  k_gemm<4, 32, 0, 1, 2, 1><<<384, 256, 0, stream>>>(
      m_, W_sage, h2, b_sage, 512, 512, 512, 512,
      2097152LL, 262144LL, 2097152LL, 512);

  // d4: head
  head_kernel<<<256, 256, 0, stream>>>(h2, W_lin, b_lin, out);
}

// Round 9
// 249.278 us; speedup vs baseline: 1.4315x; 1.0719x over previous
//
#include <hip/hip_runtime.h>

typedef __attribute__((ext_vector_type(8))) short short8;
typedef __attribute__((ext_vector_type(4))) float f32x4;

__device__ __forceinline__ unsigned short f2bf(float f) {
  union { float f; unsigned u; } v; v.f = f;
  unsigned u = v.u + 0x7fffu + ((v.u >> 16) & 1u);
  return (unsigned short)(u >> 16);
}
__device__ __forceinline__ float bflo(unsigned u) {
  union { unsigned u; float f; } v; v.u = u << 16; return v.f;
}
__device__ __forceinline__ float bfhi(unsigned u) {
  union { unsigned u; float f; } v; v.u = u & 0xffff0000u; return v.f;
}
// v_cvt_pk_bf16_f32: 2 fp32 -> packed 2 bf16 (RNE), 1 inst
__device__ __forceinline__ unsigned cvtpk(float lo, float hi) {
  unsigned r;
  asm("v_cvt_pk_bf16_f32 %0, %1, %2" : "=v"(r) : "v"(lo), "v"(hi));
  return r;
}
typedef unsigned int u32;
typedef u32 __attribute__((address_space(3)))* lds_u32p;
typedef const u32 __attribute__((address_space(1)))* glob_u32p;
__device__ __forceinline__ void glds16(const unsigned short* g, unsigned short* l) {
  __builtin_amdgcn_global_load_lds((glob_u32p)(const void*)g, (lds_u32p)(void*)l,
                                   16, 0, 0);
}
__device__ __forceinline__ void cast8(const float* p, unsigned short* o) {
  float4 f0 = *(const float4*)p;
  float4 f1 = *(const float4*)(p + 4);
  uint4 w;
  w.x = cvtpk(f0.x, f0.y); w.y = cvtpk(f0.z, f0.w);
  w.z = cvtpk(f1.x, f1.y); w.w = cvtpk(f1.z, f1.w);
  *(uint4*)o = w;
}

// ====== gemm body 128x128xBK64 — R5-proven single-buffer m97 structure ====
// C[MxN](bf16) = op(A[MxK] @ Bt[NxK]^T), both operands bf16 via
// global_load_lds_dwordx4 with pre-swizzled source col (rule #21).
// LDS elem(row,col) at [row*64 + (col ^ ((row&7)<<3))].
// BIAS_MODE: 0 none, 1 per-row, 2 per-col.
template<int GX, int GY, int BIAS_MODE, int RELU>
__device__ __forceinline__ void gemm_body(int s,
    const unsigned short* __restrict__ Ab, const unsigned short* __restrict__ Bb,
    unsigned short* __restrict__ Cv, const float* __restrict__ biasv,
    int K, int lda, int ldb, int ldc,
    long long sA, long long sB, long long sC, int sBias,
    unsigned short* lA, unsigned short* lB)
{
  const int bx = s % GX;
  const int by = (s / GX) % GY;
  const int t  = s / (GX * GY);
  const int row0 = by * 128, col0 = bx * 128;

  const unsigned short* A = Ab + (size_t)t * sA;
  const unsigned short* B = Bb + (size_t)t * sB;
  unsigned short*       C = Cv + (size_t)t * sC;

  const int tid  = threadIdx.x;
  const int lane = tid & 63;
  const int wave = tid >> 6;
  const int wr   = wave >> 1;          // 0..1 (M half)
  const int wc   = wave & 1;           // 0..1 (N half)
  const int fr   = lane & 15;
  const int fk   = (lane >> 4) << 3;
  const int grow = lane >> 3;          // glds: +row within 8-row segment
  const int gcol = (lane & 7) << 3;    // glds: stored col (pre-swizzle)

  f32x4 acc[4][4] = {};

  for (int k0 = 0; k0 < K; k0 += 64) {
    __syncthreads();
    #pragma unroll
    for (int i = 0; i < 4; ++i) {
      int seg = i * 4 + wave;
      int r   = seg * 8 + grow;
      int c   = gcol ^ ((r & 7) << 3);
      glds16(A + (size_t)(row0 + r) * lda + k0 + c, &lA[seg * 512]);
      glds16(B + (size_t)(col0 + r) * ldb + k0 + c, &lB[seg * 512]);
    }
    __syncthreads();   // compiler drains vmcnt here

    #pragma unroll
    for (int kk = 0; kk < 2; ++kk) {
      short8 af[4], bv[4];
      #pragma unroll
      for (int mi = 0; mi < 4; ++mi) {
        int r = wr * 64 + mi * 16 + fr;
        af[mi] = *(const short8*)&lA[r * 64 + ((kk * 32 + fk) ^ ((r & 7) << 3))];
      }
      #pragma unroll
      for (int ni = 0; ni < 4; ++ni) {
        int r = wc * 64 + ni * 16 + fr;
        bv[ni] = *(const short8*)&lB[r * 64 + ((kk * 32 + fk) ^ ((r & 7) << 3))];
      }
      #pragma unroll
      for (int mi = 0; mi < 4; ++mi)
        #pragma unroll
        for (int ni = 0; ni < 4; ++ni)
          acc[mi][ni] = __builtin_amdgcn_mfma_f32_16x16x32_bf16(
              af[mi], bv[ni], acc[mi][ni], 0, 0, 0);
    }
  }

  const float* bias = nullptr;
  if constexpr (BIAS_MODE != 0) bias = biasv + (size_t)t * sBias;
  const int erow = (lane >> 4) << 2;
  #pragma unroll
  for (int mi = 0; mi < 4; ++mi) {
    #pragma unroll
    for (int ni = 0; ni < 4; ++ni) {
      #pragma unroll
      for (int j = 0; j < 4; ++j) {
        int row = row0 + wr * 64 + mi * 16 + erow + j;
        int col = col0 + wc * 64 + ni * 16 + fr;
        float v = acc[mi][ni][j];
        if constexpr (BIAS_MODE == 1) v += bias[row];
        if constexpr (BIAS_MODE == 2) v += bias[col];
        if constexpr (RELU) v = fmaxf(v, 0.0f);
        C[(size_t)row * ldc + col] = f2bf(v);
      }
    }
  }
}

// bijective XCD swizzle over nwg blocks (nwg % 8 == 0)
__device__ __forceinline__ int xcd_swz(int bid, int nwg) {
  return (bid & 7) * (nwg >> 3) + (bid >> 3);
}

// ---- d0: fused cast of x, W_conv, W_sage -> bf16 (3840 blocks) -----------
__global__ __launch_bounds__(256)
void cast3_kernel(const float* __restrict__ x, const float* __restrict__ Wcf,
                  const float* __restrict__ Wsf,
                  unsigned short* __restrict__ xbf, unsigned short* __restrict__ Wc,
                  unsigned short* __restrict__ Wsg)
{
  const int g0 = blockIdx.x * 256 + threadIdx.x;     // 0..983039
  if (g0 < 786432) {
    cast8(x + (size_t)g0 * 8, xbf + (size_t)g0 * 8);
  } else if (g0 < 884736) {
    int j = g0 - 786432;
    cast8(Wcf + (size_t)j * 8, Wc + (size_t)j * 8);
  } else {
    int j = g0 - 884736;
    cast8(Wsf + (size_t)j * 8, Wsg + (size_t)j * 8);
  }
}

// ---- d1: blocks [0,384) gemm1 (all-bf16, R5 config);
//          blocks [384,2304) grid-stride adj fp32 -> bf16 cast.
__global__ __launch_bounds__(256)
void k_gemm1_adjcast(const unsigned short* __restrict__ Wc,
                     const unsigned short* __restrict__ xbf,
                     unsigned short* __restrict__ ht,
                     const float* __restrict__ b_conv,
                     const float* __restrict__ adj,
                     unsigned short* __restrict__ adjb)
{
  __shared__ __align__(16) unsigned short lA[128 * 64];
  __shared__ __align__(16) unsigned short lB[128 * 64];
  const int bid = blockIdx.x;
  if (bid < 384) {
    // gemm1: ht[t] = relu(W_conv[t] @ xs[t]^T + b_conv[t])  [512 x 4096]
    gemm_body<32, 4, 1, 1>(xcd_swz(bid, 384), Wc, xbf, ht, b_conv,
                           512, 512, 512, 4096,
                           262144LL, 2097152LL, 2097152LL, 512, lA, lB);
  } else {
    const size_t stride = (size_t)(2304 - 384) * 256;
    for (size_t i = (size_t)(bid - 384) * 256 + threadIdx.x; i < 6291456u;
         i += stride)
      cast8(adj + i * 8, adjb + i * 8);
  }
}

// ---- generic all-bf16 gemm dispatch (spmm, gemm3) ----
template<int GX, int GY, int BIAS_MODE, int RELU>
__global__ __launch_bounds__(256)
void k_gemm(const unsigned short* __restrict__ Ab,
            const unsigned short* __restrict__ Bb,
            unsigned short* __restrict__ Cv, const float* __restrict__ biasv,
            int K, int lda, int ldb, int ldc,
            long long sA, long long sB, long long sC, int sBias)
{
  __shared__ __align__(16) unsigned short lA[128 * 64];
  __shared__ __align__(16) unsigned short lB[128 * 64];
  gemm_body<GX, GY, BIAS_MODE, RELU>(
      xcd_swz(blockIdx.x, GX * GY * 3), Ab, Bb, Cv, biasv,
      K, lda, ldb, ldc, sA, sB, sC, sBias, lA, lB);
}

// ---------------- head: logits = feat @ W_lin^T + b, then log_softmax -----
__global__ __launch_bounds__(256)
void head_kernel(const unsigned short* __restrict__ h2,
                 const float* __restrict__ Wl,
                 const float* __restrict__ blin,
                 float* __restrict__ out)
{
  const int tid = threadIdx.x;
  const int c   = tid & 31;
  const int rg  = tid >> 5;
  const int i0  = blockIdx.x * 16;
  const int r0  = i0 + rg;
  const int r1  = i0 + rg + 8;
  float acc0 = 0.f, acc1 = 0.f;
  #pragma unroll
  for (int t = 0; t < 3; ++t) {
    const unsigned short* x0 = h2 + (size_t)t * 2097152 + (size_t)r0 * 512;
    const unsigned short* x1 = h2 + (size_t)t * 2097152 + (size_t)r1 * 512;
    const float* wt = Wl + (size_t)c * 1536 + t * 512;
    #pragma unroll 4
    for (int k = 0; k < 512; k += 8) {
      float4 w0 = *(const float4*)(wt + k);
      float4 w1 = *(const float4*)(wt + k + 4);
      uint4 a0 = *(const uint4*)(x0 + k);
      uint4 a1 = *(const uint4*)(x1 + k);
      const unsigned* u0 = (const unsigned*)&a0;
      const unsigned* u1 = (const unsigned*)&a1;
      const float* wf = (const float*)&w0;
      #pragma unroll
      for (int q = 0; q < 2; ++q) {
        acc0 += bflo(u0[q]) * wf[2*q] + bfhi(u0[q]) * wf[2*q+1];
        acc1 += bflo(u1[q]) * wf[2*q] + bfhi(u1[q]) * wf[2*q+1];
      }
      const float* wg = (const float*)&w1;
      #pragma unroll
      for (int q = 0; q < 2; ++q) {
        acc0 += bflo(u0[q+2]) * wg[2*q] + bfhi(u0[q+2]) * wg[2*q+1];
        acc1 += bflo(u1[q+2]) * wg[2*q] + bfhi(u1[q+2]) * wg[2*q+1];
      }
    }
  }
  acc0 += blin[c]; acc1 += blin[c];
  float m0 = acc0, m1 = acc1;
  #pragma unroll
  for (int s2 = 16; s2; s2 >>= 1) {
    m0 = fmaxf(m0, __shfl_xor(m0, s2, 32));
    m1 = fmaxf(m1, __shfl_xor(m1, s2, 32));
  }
  float e0 = expf(acc0 - m0), e1 = expf(acc1 - m1);
  #pragma unroll
  for (int s2 = 16; s2; s2 >>= 1) {
    e0 += __shfl_xor(e0, s2, 32);
    e1 += __shfl_xor(e1, s2, 32);
  }
  out[(size_t)r0 * 32 + c] = acc0 - m0 - logf(e0);
  out[(size_t)r1 * 32 + c] = acc1 - m1 - logf(e1);
}

extern "C" void kernel_launch(void* const* d_in, const int* in_sizes, int n_in,
                              void* d_out, int out_size, void* d_ws, size_t ws_size,
                              hipStream_t stream)
{
  const float* x      = (const float*)d_in[0];
  const float* adj    = (const float*)d_in[1];
  // d_in[2] = node_type_mask (unused: contiguous equal blocks by construction)
  const float* W_conv = (const float*)d_in[3];
  const float* b_conv = (const float*)d_in[4];
  const float* W_sage = (const float*)d_in[5];
  const float* b_sage = (const float*)d_in[6];
  const float* W_lin  = (const float*)d_in[7];
  const float* b_lin  = (const float*)d_in[8];
  float* out = (float*)d_out;

  // workspace (bf16 elems); h2 reuses ht (ht dead after spmm)
  unsigned short* ws   = (unsigned short*)d_ws;
  unsigned short* adjb = ws;                    // 50,331,648 (adj[0:4096,:] bf16)
  unsigned short* xbf  = adjb + 50331648;       //  6,291,456
  unsigned short* Wc   = xbf  + 6291456;        //    786,432
  unsigned short* Wsg  = Wc   + 786432;         //    786,432
  unsigned short* ht   = Wsg  + 786432;         //  6,291,456 (h^T [3][512][4096])
  unsigned short* m_   = ht   + 6291456;        //  6,291,456 ([3][4096][512])
  unsigned short* h2   = ht;

  // d0: cast x, W_conv, W_sage -> bf16 (one dispatch)
  cast3_kernel<<<3840, 256, 0, stream>>>(x, W_conv, W_sage, xbf, Wc, Wsg);

  // d1: gemm1 (all-bf16) || adj cast
  k_gemm1_adjcast<<<2304, 256, 0, stream>>>(Wc, xbf, ht, b_conv, adj, adjb);

  // d2 (spmm): m[t] = adj_b[t] @ h[t]   A=adjb (lda=12288, +t*4096 cols)
  k_gemm<4, 32, 0, 0><<<384, 256, 0, stream>>>(
      adjb, ht, m_, nullptr, 4096, 12288, 4096, 512,
      4096LL, 2097152LL, 2097152LL, 0);

  // d3: h2[t] = relu(m[t] @ W_sage[t]^T + b_sage[t])
  k_gemm<4, 32, 2, 1><<<384, 256, 0, stream>>>(
      m_, Wsg, h2, b_sage, 512, 512, 512, 512,
      2097152LL, 262144LL, 2097152LL, 512);

  // d4: head
  head_kernel<<<256, 256, 0, stream>>>(h2, W_lin, b_lin, out);
}